// Round 1
// baseline (143.958 us; speedup 1.0000x reference)
//
#include <hip/hip_runtime.h>

// MultiHeadedTrilinearAttention, MI355X — round 6.
// Chain cut 4 -> 3 kernels: prep_kernel eliminated. proj_kernel now reads the
// ORIGINAL row-major f32 weights directly (B-frag = 8 row-strided dword loads,
// 64B-coalesced across the 16 fm-lanes, cvt to f16 inline) and, for stage 1,
// converts the raw f32 inputs inline while forming A-frags. Numerically
// identical rounding points to the old prep path (cvt f32->f16 then MFMA).
// fused_attn_kernel unchanged (verified in prior rounds).
// ws layout: vpH,qpH,apH f16 | vo,qo,ao f32.

#define DIM   768
#define SEQ   128
#define NH    12
#define HW    64
#define PROJ_ELEMS (SEQ * DIM)   // 98304
#define QOUT_OFF   98304
#define AOUT_OFF   196608

typedef _Float16 f16x8 __attribute__((ext_vector_type(8)));
typedef float    f32x4 __attribute__((ext_vector_type(4)));

// ---------------- projection GEMM: 1 wave = 16x16 tile, LDS-free -----------
// C[128,768] = A[128,768]@W + b.
// A: f32 (stage 1, raw inputs) or f16 (stage 2, vpH) per a_f16 flag.
// W: ORIGINAL f32 row-major [k][n]; wf[j] = W[(fk+32s+j)*DIM + n0+fm].
// grid (8 m-tiles, 48 n-tiles, 3 matrices), 64 threads.
__global__ __launch_bounds__(64) void proj_kernel(
    const void* __restrict__ A0, const void* __restrict__ A1, const void* __restrict__ A2,
    const float* __restrict__ W0, const float* __restrict__ W1, const float* __restrict__ W2,
    const float* __restrict__ b0, const float* __restrict__ b1, const float* __restrict__ b2,
    void* __restrict__ C0, void* __restrict__ C1, void* __restrict__ C2,
    int a_f16, int out_f16)
{
    const int mat = blockIdx.z;
    const void* __restrict__ A   = (mat == 0) ? A0 : (mat == 1) ? A1 : A2;
    const float* __restrict__ W  = (mat == 0) ? W0 : (mat == 1) ? W1 : W2;
    const float* __restrict__ bb = (mat == 0) ? b0 : (mat == 1) ? b1 : b2;
    void* __restrict__ C         = (mat == 0) ? C0 : (mat == 1) ? C1 : C2;

    const int m0   = blockIdx.x * 16;
    const int n0   = blockIdx.y * 16;
    const int lane = threadIdx.x & 63;
    const int fm   = lane & 15;
    const int fk   = (lane >> 4) << 3;

    // W[fk + 32s + j][n0 + fm] == pw[(32s + j) * DIM]
    const float* __restrict__ pw = W + fk * DIM + n0 + fm;

    f32x4 acc = (f32x4){0.f, 0.f, 0.f, 0.f};

    if (a_f16) {
        const _Float16* __restrict__ pa = (const _Float16*)A + (m0 + fm) * DIM + fk;
        #pragma unroll
        for (int s = 0; s < 24; ++s) {
            const f16x8 af = *(const f16x8*)(pa + 32 * s);
            const float* __restrict__ w = pw + 32 * s * DIM;
            float w0 = w[0 * DIM], w1 = w[1 * DIM], w2 = w[2 * DIM], w3 = w[3 * DIM];
            float w4 = w[4 * DIM], w5 = w[5 * DIM], w6 = w[6 * DIM], w7 = w[7 * DIM];
            f16x8 wf;
            wf[0] = (_Float16)w0; wf[1] = (_Float16)w1;
            wf[2] = (_Float16)w2; wf[3] = (_Float16)w3;
            wf[4] = (_Float16)w4; wf[5] = (_Float16)w5;
            wf[6] = (_Float16)w6; wf[7] = (_Float16)w7;
            acc = __builtin_amdgcn_mfma_f32_16x16x32_f16(af, wf, acc, 0, 0, 0);
        }
    } else {
        const float* __restrict__ pa = (const float*)A + (m0 + fm) * DIM + fk;
        #pragma unroll
        for (int s = 0; s < 24; ++s) {
            const f32x4 alo = *(const f32x4*)(pa + 32 * s);
            const f32x4 ahi = *(const f32x4*)(pa + 32 * s + 4);
            f16x8 af;
            af[0] = (_Float16)alo[0]; af[1] = (_Float16)alo[1];
            af[2] = (_Float16)alo[2]; af[3] = (_Float16)alo[3];
            af[4] = (_Float16)ahi[0]; af[5] = (_Float16)ahi[1];
            af[6] = (_Float16)ahi[2]; af[7] = (_Float16)ahi[3];
            const float* __restrict__ w = pw + 32 * s * DIM;
            float w0 = w[0 * DIM], w1 = w[1 * DIM], w2 = w[2 * DIM], w3 = w[3 * DIM];
            float w4 = w[4 * DIM], w5 = w[5 * DIM], w6 = w[6 * DIM], w7 = w[7 * DIM];
            f16x8 wf;
            wf[0] = (_Float16)w0; wf[1] = (_Float16)w1;
            wf[2] = (_Float16)w2; wf[3] = (_Float16)w3;
            wf[4] = (_Float16)w4; wf[5] = (_Float16)w5;
            wf[6] = (_Float16)w6; wf[7] = (_Float16)w7;
            acc = __builtin_amdgcn_mfma_f32_16x16x32_f16(af, wf, acc, 0, 0, 0);
        }
    }

    const int col  = n0 + fm;
    const int row0 = m0 + ((lane >> 4) << 2);
    const float bi = bb[col];
    #pragma unroll
    for (int rr = 0; rr < 4; ++rr) {
        const float val = acc[rr] + bi;
        if (out_f16) ((_Float16*)C)[(row0 + rr) * DIM + col] = (_Float16)val;
        else         ((float*)C)[(row0 + rr) * DIM + col]    = val;
    }
}

// -------- fused MFMA scores + group softmax + marginals + outputs --------
// block = (v-token, head). S[q][a] = sum_k vq[q,k]*ah[a,k], f16 MFMA, both
// operands staged in LDS. wave w == softmax group (q in [32w,32w+32)).
// C layout: col a = at*16+fm; row q'' = qt*16 + quad*4 + rr. No max-sub
// (scores ~N(0,0.17) — exp safe). Epilogue gathers simplify to
// vo[vtok*DIM + h*64 + w*16 + bin] (contiguous).
__global__ __launch_bounds__(256) void fused_attn_kernel(
    const _Float16* __restrict__ vpH, const _Float16* __restrict__ qpH,
    const _Float16* __restrict__ apH,
    const float* __restrict__ vo, const float* __restrict__ qo, const float* __restrict__ ao,
    float* __restrict__ out)
{
    const int vtok = blockIdx.x;   // 0..127
    const int h    = blockIdx.y;   // 0..11

    __shared__ _Float16 vqL[128][72];  // [q][k] f16, pad 72
    __shared__ _Float16 ahL[128][72];  // [a][k] f16

    const int t    = threadIdx.x;
    const int w    = t >> 6;
    const int lane = t & 63;
    const int fm   = lane & 15;
    const int fk   = (lane >> 4) << 3;

    // staging: thread t -> row r = t>>1, k-half kh = (t&1)*32
    {
        const int r  = t >> 1;
        const int kh = (t & 1) << 5;
        const _Float16* pq = qpH + r    * DIM + h * HW + kh;
        const _Float16* pv = vpH + vtok * DIM + h * HW + kh;
        const _Float16* pa = apH + r    * DIM + h * HW + kh;
        #pragma unroll
        for (int u = 0; u < 4; ++u) {
            const f16x8 qv = *(const f16x8*)(pq + 8 * u);
            const f16x8 vv = *(const f16x8*)(pv + 8 * u);
            const f16x8 av = *(const f16x8*)(pa + 8 * u);
            *(f16x8*)&vqL[r][kh + 8 * u] = qv * vv;   // v_pk_mul_f16
            *(f16x8*)&ahL[r][kh + 8 * u] = av;
        }
    }
    __syncthreads();

    f32x4 acc[2][8];
    #pragma unroll
    for (int qt = 0; qt < 2; ++qt)
        #pragma unroll
        for (int at = 0; at < 8; ++at)
            acc[qt][at] = (f32x4){0.f, 0.f, 0.f, 0.f};

    const int q0 = 32 * w;
    #pragma unroll
    for (int ks = 0; ks < 2; ++ks) {
        const f16x8 af0 = *(const f16x8*)&vqL[q0 + fm     ][32 * ks + fk];
        const f16x8 af1 = *(const f16x8*)&vqL[q0 + 16 + fm][32 * ks + fk];
        #pragma unroll
        for (int at = 0; at < 8; ++at) {
            const f16x8 bf = *(const f16x8*)&ahL[16 * at + fm][32 * ks + fk];
            acc[0][at] = __builtin_amdgcn_mfma_f32_16x16x32_f16(af0, bf, acc[0][at], 0, 0, 0);
            acc[1][at] = __builtin_amdgcn_mfma_f32_16x16x32_f16(af1, bf, acc[1][at], 0, 0, 0);
        }
    }

    // exp + marginal partials (no max subtraction).
    // q'' = qt*16 + quad*4 + rr ; a = at*16 + fm
    // v-bin = q''>>1 = qt*8 + quad*2 + (rr>>1) -> sv[qt][rr>>1] (quad in lane)
    // q-bin = (rr&1)*8 + at                    -> sq[rr&1][at]  (lane-uniform)
    // a-bin = fm                               -> sa            (fm in lane)
    float sv[2][2] = {{0.f, 0.f}, {0.f, 0.f}};
    float sq[2][8];
    #pragma unroll
    for (int i = 0; i < 2; ++i)
        #pragma unroll
        for (int j = 0; j < 8; ++j) sq[i][j] = 0.f;
    float sa = 0.f;
    #pragma unroll
    for (int qt = 0; qt < 2; ++qt)
        #pragma unroll
        for (int at = 0; at < 8; ++at)
            #pragma unroll
            for (int rr = 0; rr < 4; ++rr) {
                const float e = __expf(acc[qt][at][rr] * 0.125f);
                sv[qt][rr >> 1] += e;
                sq[rr & 1][at]  += e;
                sa += e;
            }

    // --- reductions (split butterflies; validated R4) ---
    sa += __shfl_xor(sa, 16);
    sa += __shfl_xor(sa, 32);
    float tot = sa;
    tot += __shfl_xor(tot, 1);
    tot += __shfl_xor(tot, 2);
    tot += __shfl_xor(tot, 4);
    tot += __shfl_xor(tot, 8);
    const bool b0 = lane & 1;
    const bool b1 = lane & 2;
    float sF;
    {
        float snd0 = b0 ? sv[0][0] : sv[1][0];
        float snd1 = b0 ? sv[0][1] : sv[1][1];
        float r0 = __shfl_xor(snd0, 1);
        float r1 = __shfl_xor(snd1, 1);
        float s0 = (b0 ? sv[1][0] : sv[0][0]) + r0;   // qt = b0, rh = 0
        float s1 = (b0 ? sv[1][1] : sv[0][1]) + r1;   // qt = b0, rh = 1
        float snd = b1 ? s0 : s1;
        float r2 = __shfl_xor(snd, 2);
        sF = (b1 ? s1 : s0) + r2;                     // qt = b0, rh = b1
    }
    sF += __shfl_xor(sF, 4);
    sF += __shfl_xor(sF, 8);
    float s[16];
    #pragma unroll
    for (int i = 0; i < 2; ++i)
        #pragma unroll
        for (int j = 0; j < 8; ++j) s[i * 8 + j] = sq[i][j];
    #pragma unroll
    for (int k = 0; k < 4; ++k) {
        const int d = 1 << k;
        const int m = 16 >> (k + 1);
        const bool b = (lane >> k) & 1;
        #pragma unroll
        for (int x = 0; x < m; ++x) {
            const float snd = b ? s[x] : s[x + m];
            const float rcv = __shfl_xor(snd, d);
            s[x] = (b ? s[x + m] : s[x]) + rcv;
        }
    }
    s[0] += __shfl_xor(s[0], 16);
    s[0] += __shfl_xor(s[0], 32);

    const int g  = h * 512 + vtok * 4 + w;    // softmax group id
    const int b2 = g / 12;
    const int h2 = g - b2 * 12;
    const float invZ = 1.0f / tot;
    const int obase = vtok * DIM + h * HW + w * 16;   // == fetch_o(., g*16+bin)

    if (fm < 4) {                             // 16 writer lanes: v-outputs
        const int quad = lane >> 4;
        const int bin  = (fm & 1) * 8 + quad * 2 + ((fm >> 1) & 1);
        out[(b2 * 16 + bin) * 12 + h2] = sF * invZ * vo[obase + bin];
    }
    if (lane < 16) {                          // 16 writer lanes: q- and a-outputs
        const int qbin = 8 * (lane & 1) + 4 * ((lane >> 1) & 1)
                       + 2 * ((lane >> 2) & 1) + (lane >> 3);
        out[QOUT_OFF + (b2 * 16 + qbin) * 12 + h2] = s[0] * invZ * qo[obase + qbin];
        out[AOUT_OFF + (b2 * 16 + lane) * 12 + h2] = sa   * invZ * ao[obase + lane];
    }
}

extern "C" void kernel_launch(void* const* d_in, const int* in_sizes, int n_in,
                              void* d_out, int out_size, void* d_ws, size_t ws_size,
                              hipStream_t stream)
{
    const float* v   = (const float*)d_in[0];
    const float* q   = (const float*)d_in[1];
    const float* a   = (const float*)d_in[2];
    // d_in[3..5] = masks, unused by the reference forward
    const float* Wv  = (const float*)d_in[6];
    const float* bv  = (const float*)d_in[7];
    const float* Wq  = (const float*)d_in[8];
    const float* bq  = (const float*)d_in[9];
    const float* Wa  = (const float*)d_in[10];
    const float* ba  = (const float*)d_in[11];
    const float* Wvo = (const float*)d_in[12];
    const float* bvo = (const float*)d_in[13];
    const float* Wqo = (const float*)d_in[14];
    const float* bqo = (const float*)d_in[15];
    const float* Wao = (const float*)d_in[16];
    const float* bao = (const float*)d_in[17];

    float* out = (float*)d_out;

    _Float16* vpH = (_Float16*)d_ws;
    _Float16* qpH = vpH + PROJ_ELEMS;
    _Float16* apH = qpH + PROJ_ELEMS;
    float*    vo  = (float*)(apH + PROJ_ELEMS);
    float*    qo  = vo + PROJ_ELEMS;
    float*    ao  = qo + PROJ_ELEMS;

    // 1) stage-1 projections (f32 inputs + f32 weights read directly, f16 out)
    proj_kernel<<<dim3(8, 48, 3), 64, 0, stream>>>(
        v, q, a, Wv, Wq, Wa,
        bv, bq, ba, vpH, qpH, apH, 0, 1);
    // 2) stage-2 projections (f16 A, f32 weights read directly, f32 out)
    proj_kernel<<<dim3(8, 48, 3), 64, 0, stream>>>(
        vpH, qpH, apH, Wvo, Wqo, Wao,
        bvo, bqo, bao, vo, qo, ao, 1, 0);
    // 3) fused trilinear scores + grouped softmax + marginal outputs
    fused_attn_kernel<<<dim3(SEQ, NH), 256, 0, stream>>>(
        vpH, qpH, apH, vo, qo, ao, out);
}